// Round 21
// baseline (1680.187 us; speedup 1.0000x reference)
//
#include <hip/hip_runtime.h>
#include <hip/hip_bf16.h>
#include <math.h>

#define HID 4096
#define NH 128
#define HD 64
#define DIN 8192      // NH*HD
#define G 8
#define NSTATE 128
#define CS 256
#define GROUP_SIZE 1024
#define CONV_DIM 10240  // DIN + 2*G*NSTATE
#define ZXW 18432       // DIN + CONV_DIM = 72*256 (dt columns handled by fp32 path)
#define BATCH 2
#define SEQ 2048
#define NT (BATCH*SEQ)  // 4096 tokens
#define NC 8            // SEQ/CS
#define DTSK 16         // split-K factor for the fp32 dt GEMM

typedef __attribute__((ext_vector_type(8))) short bf16x8;
typedef __attribute__((ext_vector_type(4))) float f32x4;
typedef __attribute__((ext_vector_type(8))) unsigned short u16x8;
typedef __attribute__((ext_vector_type(4))) unsigned short u16x4;

__device__ __forceinline__ float sigmoidf_(float x){ return 1.f/(1.f+expf(-x)); }
__device__ __forceinline__ float siluf_(float x){ return x*sigmoidf_(x); }
__device__ __forceinline__ float softplusf_(float x){ return (x>20.f)? x : log1pf(expf(x)); }
__device__ __forceinline__ float b2f(unsigned short u){ union{unsigned int i; float f;} x; x.i = ((unsigned int)u)<<16; return x.f; }
__device__ __forceinline__ unsigned short f2b(float f){ __hip_bfloat16 h = __float2bfloat16(f); return *(unsigned short*)&h; }

__device__ __forceinline__ void gload_lds16(const void* g, void* l) {
  __builtin_amdgcn_global_load_lds((const __attribute__((address_space(1))) unsigned int*)g,
                                   (__attribute__((address_space(3))) unsigned int*)l, 16, 0, 0);
}
__device__ __forceinline__ bf16x8 ld8bf(const __hip_bfloat16* p){ return *(const bf16x8*)p; }

__device__ __forceinline__ void cast8(const float* in, __hip_bfloat16* out) {
  const float4* p = (const float4*)in;
  float4 a = p[0], b = p[1];
  union { __hip_bfloat16 h[8]; int4 v; } o;
  o.h[0]=__float2bfloat16(a.x); o.h[1]=__float2bfloat16(a.y);
  o.h[2]=__float2bfloat16(a.z); o.h[3]=__float2bfloat16(a.w);
  o.h[4]=__float2bfloat16(b.x); o.h[5]=__float2bfloat16(b.y);
  o.h[6]=__float2bfloat16(b.z); o.h[7]=__float2bfloat16(b.w);
  *(int4*)out = o.v;
}

// ---------------- 256x256 bf16 MFMA GEMM, 2-phase interleave, counted vmcnt ----------------
// (round-8 schedule: best measured across 8 variants; 727us in_proj, MfmaUtil 37%, conflicts 0.
//  GEMM CLOSED.)
template<bool OUT_BF16>
__global__ __launch_bounds__(512)
void gemm_bf16_256(const __hip_bfloat16* __restrict__ A, const __hip_bfloat16* __restrict__ B,
                   void* __restrict__ Cout, int M, int N, int K) {
  const int nMt = M >> 8, nNt = N >> 8;
  const int nwg = nMt * nNt;
  const int cpx = nwg >> 3;
  const int lin = blockIdx.x;
  const int swz = (lin & 7) * cpx + (lin >> 3);   // XCD-chunked (nwg%8==0)
  const int mt = swz % nMt, ntile = swz / nMt;    // M fastest -> B panel L2-hot
  const int rowBase = mt << 8;
  const int colBase = ntile << 8;

  __shared__ short As[4][8192];   // 4 x 16KB
  __shared__ short Bs[4][8192];

  const int tid = threadIdx.x;
  const int lane = tid & 63, wid = tid >> 6;
  const int wr = wid >> 2, wc = wid & 3;          // 2M x 4N wave grid
  const int l15 = lane & 15, l4 = lane >> 4;

  const int r0 = tid >> 2,        c0 = (tid & 3) ^ ((r0 >> 1) & 3);
  const int r1 = (512+tid) >> 2,  c1 = ((512+tid) & 3) ^ ((r1 >> 1) & 3);
  const __hip_bfloat16* gA0 = A + (size_t)(rowBase + r0)*K + c0*8;
  const __hip_bfloat16* gA1 = A + (size_t)(rowBase + r1)*K + c1*8;
  const __hip_bfloat16* gB0 = B + (size_t)(colBase + r0)*K + c0*8;
  const __hip_bfloat16* gB1 = B + (size_t)(colBase + r1)*K + c1*8;
  const int ld0 = wid*512, ld1 = 4096 + wid*512;

#define STAGE_A(q, kt) do { \
    gload_lds16(gA0 + (size_t)(kt)*32, (void*)&As[q][ld0]); \
    gload_lds16(gA1 + (size_t)(kt)*32, (void*)&As[q][ld1]); \
  } while(0)
#define STAGE_B(q, kt) do { \
    gload_lds16(gB0 + (size_t)(kt)*32, (void*)&Bs[q][ld0]); \
    gload_lds16(gB1 + (size_t)(kt)*32, (void*)&Bs[q][ld1]); \
  } while(0)

  int aoff[8], boff[4];
  #pragma unroll
  for (int m=0;m<8;++m){ int r = wr*128 + m*16 + l15; aoff[m] = r*32 + ((l4 ^ ((r>>1)&3))*8); }
  #pragma unroll
  for (int n=0;n<4;++n){ int r = wc*64  + n*16 + l15; boff[n] = r*32 + ((l4 ^ ((r>>1)&3))*8); }

  f32x4 acc[8][4] = {};
  const int NKT = K >> 5;

  STAGE_A(0,0); STAGE_B(0,0);
  STAGE_A(1,1); STAGE_B(1,1);
  STAGE_A(2,2); STAGE_B(2,2);
  asm volatile("s_waitcnt vmcnt(8)" ::: "memory");
  __builtin_amdgcn_s_barrier();

  for (int t = 0; t < NKT; ++t) {
    const short* ab = &As[t&3][0];
    const short* bb = &Bs[t&3][0];
    const int q3 = (t+3)&3;
    bf16x8 a[4], b[4], a2[4];
    // phase A
    #pragma unroll
    for (int m=0;m<4;++m) a[m] = *(const bf16x8*)&ab[aoff[m]];
    #pragma unroll
    for (int n=0;n<4;++n) b[n] = *(const bf16x8*)&bb[boff[n]];
    if (t + 3 < NKT) STAGE_A(q3, t+3);
    __builtin_amdgcn_s_barrier();
    asm volatile("s_waitcnt lgkmcnt(0)" ::: "memory");
    __builtin_amdgcn_sched_barrier(0);
    __builtin_amdgcn_s_setprio(1);
    #pragma unroll
    for (int m=0;m<4;++m)
      #pragma unroll
      for (int n=0;n<4;++n)
        acc[m][n] = __builtin_amdgcn_mfma_f32_16x16x32_bf16(a[m], b[n], acc[m][n], 0, 0, 0);
    __builtin_amdgcn_s_setprio(0);
    __builtin_amdgcn_s_barrier();
    // phase B
    #pragma unroll
    for (int m=0;m<4;++m) a2[m] = *(const bf16x8*)&ab[aoff[m+4]];
    if (t + 3 < NKT) STAGE_B(q3, t+3);
    const int rem = NKT - 1 - t;
    if (rem >= 3)      asm volatile("s_waitcnt vmcnt(8)" ::: "memory");
    else if (rem == 2) asm volatile("s_waitcnt vmcnt(4)" ::: "memory");
    else if (rem == 1) asm volatile("s_waitcnt vmcnt(0)" ::: "memory");
    __builtin_amdgcn_s_barrier();
    asm volatile("s_waitcnt lgkmcnt(0)" ::: "memory");
    __builtin_amdgcn_sched_barrier(0);
    __builtin_amdgcn_s_setprio(1);
    #pragma unroll
    for (int m=0;m<4;++m)
      #pragma unroll
      for (int n=0;n<4;++n)
        acc[m+4][n] = __builtin_amdgcn_mfma_f32_16x16x32_bf16(a2[m], b[n], acc[m+4][n], 0, 0, 0);
    __builtin_amdgcn_s_setprio(0);
    __builtin_amdgcn_s_barrier();
  }
#undef STAGE_A
#undef STAGE_B

  #pragma unroll
  for (int m=0;m<8;++m) {
    int row0 = rowBase + wr*128 + m*16 + l4*4;
    #pragma unroll
    for (int n=0;n<4;++n) {
      int col = colBase + wc*64 + n*16 + l15;
      #pragma unroll
      for (int j=0;j<4;++j) {
        if (OUT_BF16)
          ((__hip_bfloat16*)Cout)[(size_t)(row0+j)*N + col] = __float2bfloat16(acc[m][n][j]);
        else
          ((float*)Cout)[(size_t)(row0+j)*N + col] = acc[m][n][j];
      }
    }
  }
}

// ---------------- fp32 dt GEMM, split-K; emits hs_bf AND both weight casts ----------------
__global__ __launch_bounds__(256)
void dt_gemm_splitk(const float* __restrict__ A, const float* __restrict__ B,
                    float* __restrict__ partial, __hip_bfloat16* __restrict__ hs_bf,
                    const float* __restrict__ w_in, __hip_bfloat16* __restrict__ w_in_bf,
                    const float* __restrict__ w_out, __hip_bfloat16* __restrict__ w_out_bf) {
  __shared__ float As[16][132];
  __shared__ float Bs[16][132];
  const int tid = threadIdx.x;
  const int tx = tid & 15, ty = tid >> 4;
  const int rowBase = blockIdx.y * 128;
  const int k0 = blockIdx.x * (HID/DTSK);
  float acc[8][8] = {};
  for (int kt = k0; kt < k0 + HID/DTSK; kt += 16) {
    for (int e = tid; e < 128*16; e += 256) {
      int r = e >> 4, c = e & 15;
      float av = A[(size_t)(rowBase + r) * HID + kt + c];
      As[c][r] = av;
      hs_bf[(size_t)(rowBase + r) * HID + kt + c] = __float2bfloat16(av);
      Bs[c][r] = B[(size_t)r * HID + kt + c];
    }
    __syncthreads();
    #pragma unroll
    for (int kk = 0; kk < 16; ++kk) {
      float a[8], bv[8];
      #pragma unroll
      for (int i = 0; i < 8; ++i) a[i] = As[kk][ty*8+i];
      #pragma unroll
      for (int j = 0; j < 8; ++j) bv[j] = Bs[kk][tx*8+j];
      #pragma unroll
      for (int i = 0; i < 8; ++i)
        #pragma unroll
        for (int j = 0; j < 8; ++j)
          acc[i][j] += a[i]*bv[j];
    }
    __syncthreads();
  }
  float* outp = partial + (size_t)blockIdx.x * NT * NH;
  for (int i = 0; i < 8; ++i) {
    size_t ro = (size_t)(rowBase + ty*8 + i) * NH + tx*8;
    #pragma unroll
    for (int j = 0; j < 8; ++j) outp[ro + j] = acc[i][j];
  }
  // ---- fused weight casts (grid-stride over both weight matrices) ----
  {
    const size_t n1 = (size_t)ZXW*HID/8;
    const size_t n2 = (size_t)HID*DIN/8;
    const size_t ntot = n1 + n2;
    size_t gid = ((size_t)blockIdx.y * gridDim.x + blockIdx.x) * 256 + tid;
    size_t gsz = (size_t)gridDim.x * gridDim.y * 256;
    for (size_t i = gid; i < ntot; i += gsz) {
      if (i < n1)  cast8(w_in + i*8,      w_in_bf + i*8);
      else         cast8(w_out+ (i-n1)*8, w_out_bf+ (i-n1)*8);
    }
  }
}

// ---------------- dt: split-K reduce + softplus + per-chunk cumsum ----------------
__global__ __launch_bounds__(256)
void dt_scan_kernel(const float* __restrict__ partial, const float* __restrict__ dt_bias,
                    const float* __restrict__ A_log, float* __restrict__ dt_sp,
                    float* __restrict__ Acs) {
  int bid = blockIdx.x;       // (b*NH + h)*NC + c
  int c = bid % NC;
  int h = (bid / NC) % NH;
  int b = bid / (NC*NH);
  int k = threadIdx.x;
  int t = b*SEQ + c*CS + k;
  float raw = dt_bias[h];
  #pragma unroll
  for (int sk = 0; sk < DTSK; ++sk) raw += partial[(size_t)sk*NT*NH + (size_t)t*NH + h];
  float dtv = softplusf_(raw);
  dt_sp[(size_t)t*NH + h] = dtv;
  float adt = -expf(A_log[h]) * dtv;
  __shared__ float s[CS];
  s[k] = adt;
  __syncthreads();
  for (int off = 1; off < CS; off <<= 1) {
    float v = (k >= off) ? s[k-off] : 0.f;
    __syncthreads();
    s[k] += v;
    __syncthreads();
  }
  Acs[((size_t)(b*NH + h)*NC + c)*CS + k] = s[k];
}

// ---------------- fused conv+SiLU + transpose + dt scaling ----------------
__global__ __launch_bounds__(256)
void conv_fused_kernel(const __hip_bfloat16* __restrict__ zx, const float* __restrict__ w,
                       const float* __restrict__ bias,
                       const float* __restrict__ dt_sp, const float* __restrict__ Acs,
                       __hip_bfloat16* __restrict__ xsT, __hip_bfloat16* __restrict__ xwT,
                       __hip_bfloat16* __restrict__ Bbf, __hip_bfloat16* __restrict__ Cbf,
                       __hip_bfloat16* __restrict__ BT) {
  const int tt = blockIdx.x;
  const int ct = blockIdx.y;
  const int t0 = tt*64;
  const int ch0 = ct*64;
  const int tid = threadIdx.x;
  __shared__ unsigned short T[64][72];
  __shared__ float dts[64], ews[64];

  const bool isX = (ch0 < DIN);
  const bool isB = (ch0 >= DIN) && (ch0 < DIN + G*NSTATE);

  if (isX && tid < 64) {
    int h = ch0 >> 6;
    int t = t0 + tid;
    dts[tid] = dt_sp[(size_t)t*NH + h];
    int b = t0 >> 11, cc = (t0 >> 8) & 7, k0 = t0 & 255;
    const float* acs = Acs + ((size_t)(b*NH+h)*NC + cc)*CS;
    ews[tid] = __expf(acs[CS-1] - acs[k0 + tid]);
  }

  const int l0 = t0 & (SEQ-1);
  #pragma unroll
  for (int it = 0; it < 2; ++it) {
    int r = tid >> 2;
    int c8 = (tid & 3) + it*4;
    int cb = ch0 + c8*8;
    float acc[8];
    *(float4*)&acc[0] = *(const float4*)&bias[cb];
    *(float4*)&acc[4] = *(const float4*)&bias[cb+4];
    float4 wv[8];
    #pragma unroll
    for (int q=0;q<8;++q) wv[q] = *(const float4*)&w[(cb+q)*4];
    #pragma unroll
    for (int k=0;k<4;++k) {
      if (l0 + r - 3 + k >= 0) {
        u16x8 v = *(const u16x8*)&zx[(size_t)(t0+r-3+k)*ZXW + DIN + cb];
        #pragma unroll
        for (int q=0;q<8;++q) acc[q] += b2f(v[q]) * ((const float*)&wv[q])[k];
      }
    }
    u16x8 o;
    #pragma unroll
    for (int q=0;q<8;++q) o[q] = f2b(siluf_(acc[q]));
    if (isX || isB) {
      #pragma unroll
      for (int q=0;q<8;++q) T[c8*8+q][r] = o[q];
    }
    if (!isX) {
      if (isB) *(u16x8*)&Bbf[(size_t)(t0+r)*(G*NSTATE) + (cb - DIN)] = o;
      else     *(u16x8*)&Cbf[(size_t)(t0+r)*(G*NSTATE) + (cb - DIN - G*NSTATE)] = o;
    }
  }
  if (!isX && !isB) return;
  __syncthreads();
  #pragma unroll
  for (int it = 0; it < 2; ++it) {
    int ch = tid >> 2;
    int tc = (tid & 3) + it*4;
    u16x8 v = *(const u16x8*)&T[ch][tc*8];
    if (isX) {
      u16x8 a, wv2;
      #pragma unroll
      for (int q=0;q<8;++q) {
        float f = b2f(v[q]);
        float fs = f * dts[tc*8+q];
        a[q]   = f2b(fs);
        wv2[q] = f2b(fs * ews[tc*8+q]);
      }
      *(u16x8*)&xsT[(size_t)(ch0+ch)*NT + t0 + tc*8] = a;
      *(u16x8*)&xwT[(size_t)(ch0+ch)*NT + t0 + tc*8] = wv2;
    } else {
      *(u16x8*)&BT[(size_t)(ch0 - DIN + ch)*NT + t0 + tc*8] = v;
    }
  }
}

// ---------------- chunk states + recurrence, fused; 4 quadrants per (h,b) ----------------
// grid (NH, BATCH, 4): z = quadrant, d-half = (z&1)*32, n-half = (z>>1)*64.
// Per block: 32 d-rows (tm 0..1) x 64 n-cols (4 waves x 16). 1024 blocks = 4 waves/SIMD
// (vs 1 before). Recurrence is per-element over chunks -> partition is bit-identical.
__global__ __launch_bounds__(256)
void chunk_states_fused(const __hip_bfloat16* __restrict__ xwT, const __hip_bfloat16* __restrict__ BT,
                        const float* __restrict__ Acs, __hip_bfloat16* __restrict__ states_bf) {
  int h = blockIdx.x, b = blockIdx.y, z = blockIdx.z;
  int dh = (z & 1) * 32;
  int nh2 = (z >> 1) * 64;
  int g = h >> 4;
  int tid = threadIdx.x, lane = tid & 63, w = tid >> 6;
  int l15 = lane & 15, l4 = lane >> 4;
  int n0 = nh2 + w*16;
  f32x4 S[2] = {};
  for (int c = 0; c < NC; ++c) {
    int tbase = b*SEQ + c*CS;
    const __hip_bfloat16* xp = xwT + (size_t)(h*64 + dh + l15)*NT + tbase + l4*8;
    const __hip_bfloat16* bp = BT + (size_t)(g*128 + n0 + l15)*NT + tbase + l4*8;
    f32x4 acc[2] = {};
    for (int kc = 0; kc < 8; ++kc) {
      bf16x8 xf[2], bf1;
      #pragma unroll
      for (int tm=0;tm<2;++tm) xf[tm] = ld8bf(xp + (size_t)(tm*16)*NT + kc*32);
      bf1 = ld8bf(bp + kc*32);
      #pragma unroll
      for (int tm=0;tm<2;++tm)
        acc[tm] = __builtin_amdgcn_mfma_f32_16x16x32_bf16(xf[tm], bf1, acc[tm], 0, 0, 0);
    }
    __hip_bfloat16* out = states_bf + ((size_t)(b*NC + c)*NH + h)*(HD*NSTATE);
    float decay = expf(Acs[((size_t)(b*NH+h)*NC + c)*CS + CS-1]);
    #pragma unroll
    for (int tm=0;tm<2;++tm)
      #pragma unroll
      for (int q=0;q<4;++q) {
        out[(size_t)(dh + tm*16 + l4*4 + q)*NSTATE + n0 + l15] = __float2bfloat16(S[tm][q]);
        S[tm][q] = S[tm][q]*decay + acc[tm][q];
      }
  }
}

// ---------------- Y via MFMA — load-balanced 32-row i-tiles ----------------
__global__ __launch_bounds__(256)
void y_mfma_kernel(const __hip_bfloat16* __restrict__ zx,
                   const __hip_bfloat16* __restrict__ Cn,
                   const __hip_bfloat16* __restrict__ Bn,
                   const __hip_bfloat16* __restrict__ xsT,
                   const __hip_bfloat16* __restrict__ Sbf,
                   const float* __restrict__ dt_sp,
                   const float* __restrict__ Acs,
                   const float* __restrict__ Dp,
                   __hip_bfloat16* __restrict__ ybf) {
  int h = blockIdx.x;
  int bc = blockIdx.y;
  int c = bc & 7, b = bc >> 3;
  int g = h >> 4;
  int tbase = b*SEQ + c*CS;
  int tid = threadIdx.x, lane = tid & 63, w = tid >> 6;
  int l15 = lane & 15, l4 = lane >> 4;
  __shared__ float acs_s[CS];
  __shared__ unsigned short P[4][32][40];   // per-wave 32x32 P tile
  acs_s[tid] = Acs[((size_t)(b*NH+h)*NC + c)*CS + tid];
  __syncthreads();

  float Dh = Dp[h];
  const __hip_bfloat16* Cbase = Cn + (size_t)tbase*1024 + g*128;
  const __hip_bfloat16* Bbase = Bn + (size_t)tbase*1024 + g*128;
  const __hip_bfloat16* xbase = xsT + (size_t)(h*64 + l15)*NT + tbase;
  const __hip_bfloat16* Sb = Sbf + ((size_t)bc*NH + h)*(HD*NSTATE);

  for (int tix = 0; tix < 2; ++tix) {
    const int kt = tix ? (7 - w) : w;        // owned 32-row i-tile index
    const int i0 = kt * 32;
    float acs_i[2], rd2[2];
    #pragma unroll
    for (int ti=0;ti<2;++ti) {
      int ig = i0 + ti*16 + l15;
      acs_i[ti] = acs_s[ig];
      rd2[ti] = Dh / dt_sp[(size_t)(tbase+ig)*NH + h];
    }
    bf16x8 cfr[4][2];   // [kc][ti], reused for scores and Y_off
    #pragma unroll
    for (int kc = 0; kc < 4; ++kc)
      #pragma unroll
      for (int ti=0;ti<2;++ti)
        cfr[kc][ti] = ld8bf(Cbase + (size_t)(i0 + ti*16 + l15)*1024 + kc*32 + l4*8);

    f32x4 accY[4][2] = {};
    for (int jb = 0; jb <= kt; ++jb) {
      int j0 = jb*32;
      f32x4 sacc[2][2] = {};
      for (int kc = 0; kc < 4; ++kc) {
        bf16x8 bfr[2];
        #pragma unroll
        for (int tj=0;tj<2;++tj) bfr[tj] = ld8bf(Bbase + (size_t)(j0 + tj*16 + l15)*1024 + kc*32 + l4*8);
        #pragma unroll
        for (int tj=0;tj<2;++tj)
          #pragma unroll
          for (int ti=0;ti<2;++ti)
            sacc[tj][ti] = __builtin_amdgcn_mfma_f32_16x16x32_bf16(bfr[tj], cfr[kc][ti], sacc[tj][ti], 0, 0, 0);
      }
      if (jb < kt) {
        #pragma unroll
        for (int tj=0;tj<2;++tj)
          #pragma unroll
          for (int ti=0;ti<2;++ti) {
            float ai = acs_i[ti];
            u16x4 pk;
            #pragma unroll
            for (int q=0;q<4;++q) {
              int jg = j0 + tj*16 + l4*4 + q;
              pk[q] = f2b(sacc[tj][ti][q] * __expf(ai - acs_s[jg]));
            }
            *(u16x4*)&P[w][ti*16 + l15][tj*16 + l4*4] = pk;
          }
      } else {
        #pragma unroll
        for (int tj=0;tj<2;++tj)
          #pragma unroll
          for (int ti=0;ti<2;++ti) {
            int ig = i0 + ti*16 + l15;
            float ai = acs_i[ti];
            u16x4 pk;
            #pragma unroll
            for (int q=0;q<4;++q) {
              int jg = j0 + tj*16 + l4*4 + q;
              float v = (jg <= ig) ? sacc[tj][ti][q] * __expf(ai - acs_s[jg]) : 0.f;
              if (jg == ig) v += rd2[ti];
              pk[q] = f2b(v);
            }
            *(u16x4*)&P[w][ti*16 + l15][tj*16 + l4*4] = pk;
          }
      }
      // PV: one K=32 step over this 32-j block
      bf16x8 xf[4], pf[2];
      #pragma unroll
      for (int tm=0;tm<4;++tm) xf[tm] = ld8bf(xbase + (size_t)(tm*16)*NT + j0 + l4*8);
      #pragma unroll
      for (int ti=0;ti<2;++ti) pf[ti] = *(const bf16x8*)&P[w][ti*16 + l15][l4*8];
      #pragma unroll
      for (int tm=0;tm<4;++tm)
        #pragma unroll
        for (int ti=0;ti<2;++ti)
          accY[tm][ti] = __builtin_amdgcn_mfma_f32_16x16x32_bf16(xf[tm], pf[ti], accY[tm][ti], 0, 0, 0);
    }
    // Y_off: reuse cfr
    f32x4 oacc[4][2] = {};
    #pragma unroll
    for (int kc = 0; kc < 4; ++kc) {
      bf16x8 sf[4];
      #pragma unroll
      for (int tm=0;tm<4;++tm) sf[tm] = ld8bf(Sb + (size_t)(tm*16 + l15)*NSTATE + kc*32 + l4*8);
      #pragma unroll
      for (int tm=0;tm<4;++tm)
        #pragma unroll
        for (int ti=0;ti<2;++ti)
          oacc[tm][ti] = __builtin_amdgcn_mfma_f32_16x16x32_bf16(sf[tm], cfr[kc][ti], oacc[tm][ti], 0, 0, 0);
    }
    // epilogue for this tile
    #pragma unroll
    for (int ti=0;ti<2;++ti) {
      int ig = i0 + ti*16 + l15;
      int t = tbase + ig;
      float sd = __expf(acs_i[ti]);
      #pragma unroll
      for (int tm=0;tm<4;++tm) {
        int ch0 = h*64 + tm*16 + l4*4;
        u16x4 gv = *(const u16x4*)&zx[(size_t)t*ZXW + ch0];
        u16x4 out;
        #pragma unroll
        for (int q=0;q<4;++q) {
          float yv = accY[tm][ti][q] + sd * oacc[tm][ti][q];
          yv *= siluf_(b2f(gv[q]));
          out[q] = f2b(yv);
        }
        *(u16x4*)&ybf[(size_t)t*DIN + ch0] = out;
      }
    }
  }
}

// ---------------- RMS groupnorm, bf16 in-place ----------------
__global__ __launch_bounds__(256)
void groupnorm_bf16_kernel(unsigned short* __restrict__ y, const float* __restrict__ norm_w) {
  int bid = blockIdx.x;
  int g = bid % G;
  int t = bid / G;
  unsigned short* yp = y + (size_t)t*DIN + g*GROUP_SIZE;
  int tid = threadIdx.x;
  u16x4 v = *(const u16x4*)&yp[tid*4];
  float f[4]; float ss = 0.f;
  #pragma unroll
  for (int j=0;j<4;++j) { f[j] = b2f(v[j]); ss += f[j]*f[j]; }
  #pragma unroll
  for (int off = 32; off > 0; off >>= 1) ss += __shfl_xor(ss, off);
  __shared__ float wsum[4];
  int wave = tid >> 6;
  if ((tid & 63) == 0) wsum[wave] = ss;
  __syncthreads();
  float tot = wsum[0]+wsum[1]+wsum[2]+wsum[3];
  float rs = rsqrtf(tot/(float)GROUP_SIZE + 1e-5f);
  const float* nw = norm_w + g*GROUP_SIZE + tid*4;
  u16x4 o;
  #pragma unroll
  for (int j=0;j<4;++j) o[j] = f2b(f[j] * rs * nw[j]);
  *(u16x4*)&yp[tid*4] = o;
}

extern "C" void kernel_launch(void* const* d_in, const int* in_sizes, int n_in,
                              void* d_out, int out_size, void* d_ws, size_t ws_size,
                              hipStream_t stream) {
  const float* hs        = (const float*)d_in[0];
  const float* in_proj_w = (const float*)d_in[1];
  const float* conv_w    = (const float*)d_in[2];
  const float* conv_b    = (const float*)d_in[3];
  const float* dt_bias   = (const float*)d_in[4];
  const float* A_log     = (const float*)d_in[5];
  const float* Dp        = (const float*)d_in[6];
  const float* norm_w    = (const float*)d_in[7];
  const float* out_proj_w= (const float*)d_in[8];
  float* outp = (float*)d_out;

  char* ws = (char*)d_ws;
  __hip_bfloat16* zx_bf = (__hip_bfloat16*)ws;                      // NT*ZXW*2 = 150,994,944
  char* p = ws + (size_t)NT*ZXW*2;
  __hip_bfloat16* B_bf  = (__hip_bfloat16*)p; p += (size_t)NT*G*NSTATE*2;
  __hip_bfloat16* C_bf  = (__hip_bfloat16*)p; p += (size_t)NT*G*NSTATE*2;
  __hip_bfloat16* BT    = (__hip_bfloat16*)p; p += (size_t)NT*G*NSTATE*2;
  __hip_bfloat16* y_bf  = (__hip_bfloat16*)p; p += (size_t)NT*DIN*2;
  float* dtb    = (float*)p;  p += (size_t)NT*NH*4;
  float* Acs    = (float*)p;  p += (size_t)BATCH*NH*NC*CS*4;
  float* dt_part = (float*)y_bf;     // aliases y_bf (dead until y_mfma)
  char* F = p;
  __hip_bfloat16* w_in_bf   = (__hip_bfloat16*)F;
  __hip_bfloat16* xsT       = (__hip_bfloat16*)F;
  __hip_bfloat16* xwT       = (__hip_bfloat16*)(F + 67108864);
  __hip_bfloat16* hs_bf     = (__hip_bfloat16*)(F + 150994944);
  __hip_bfloat16* states_bf = (__hip_bfloat16*)(F + 150994944);
  char* F2 = F + 150994944 + 33554432;
  __hip_bfloat16* w_out_bf  = (__hip_bfloat16*)F2;

  // dt GEMM (fp32) + hs cast + both weight casts, all in one launch
  dt_gemm_splitk<<<dim3(DTSK, NT/128), 256, 0, stream>>>(
      hs, in_proj_w + (size_t)ZXW*HID, dt_part, hs_bf,
      in_proj_w, w_in_bf, out_proj_w, w_out_bf);
  dt_scan_kernel<<<BATCH*NH*NC, CS, 0, stream>>>(dt_part, dt_bias, A_log, dtb, Acs);

  gemm_bf16_256<true><<<dim3((NT/256)*(ZXW/256)), 512, 0, stream>>>(
      hs_bf, w_in_bf, zx_bf, NT, ZXW, HID);

  conv_fused_kernel<<<dim3(NT/64, CONV_DIM/64), 256, 0, stream>>>(
      zx_bf, conv_w, conv_b, dtb, Acs, xsT, xwT, B_bf, C_bf, BT);

  chunk_states_fused<<<dim3(NH, BATCH, 4), 256, 0, stream>>>(xwT, BT, Acs, states_bf);

  y_mfma_kernel<<<dim3(NH, BATCH*NC), 256, 0, stream>>>(zx_bf, C_bf, B_bf, xsT, states_bf, dtb, Acs, Dp, y_bf);
  groupnorm_bf16_kernel<<<NT*G, 256, 0, stream>>>((unsigned short*)y_bf, norm_w);

  gemm_bf16_256<false><<<dim3((NT/256)*(HID/256)), 512, 0, stream>>>(
      y_bf, w_out_bf, outp, NT, HID, DIN);
}

// Round 22
// 1645.609 us; speedup vs baseline: 1.0210x; 1.0210x over previous
//
#include <hip/hip_runtime.h>
#include <hip/hip_bf16.h>
#include <math.h>

#define HID 4096
#define NH 128
#define HD 64
#define DIN 8192      // NH*HD
#define G 8
#define NSTATE 128
#define CS 256
#define GROUP_SIZE 1024
#define CONV_DIM 10240  // DIN + 2*G*NSTATE
#define ZXW 18432       // DIN + CONV_DIM = 72*256 (dt columns handled by fp32 path)
#define BATCH 2
#define SEQ 2048
#define NT (BATCH*SEQ)  // 4096 tokens
#define NC 8            // SEQ/CS
#define DTSK 16         // split-K factor for the fp32 dt GEMM

typedef __attribute__((ext_vector_type(8))) short bf16x8;
typedef __attribute__((ext_vector_type(4))) float f32x4;
typedef __attribute__((ext_vector_type(8))) unsigned short u16x8;
typedef __attribute__((ext_vector_type(4))) unsigned short u16x4;

__device__ __forceinline__ float sigmoidf_(float x){ return 1.f/(1.f+expf(-x)); }
__device__ __forceinline__ float siluf_(float x){ return x*sigmoidf_(x); }
__device__ __forceinline__ float softplusf_(float x){ return (x>20.f)? x : log1pf(expf(x)); }
__device__ __forceinline__ float b2f(unsigned short u){ union{unsigned int i; float f;} x; x.i = ((unsigned int)u)<<16; return x.f; }
__device__ __forceinline__ unsigned short f2b(float f){ __hip_bfloat16 h = __float2bfloat16(f); return *(unsigned short*)&h; }

__device__ __forceinline__ void gload_lds16(const void* g, void* l) {
  __builtin_amdgcn_global_load_lds((const __attribute__((address_space(1))) unsigned int*)g,
                                   (__attribute__((address_space(3))) unsigned int*)l, 16, 0, 0);
}
__device__ __forceinline__ bf16x8 ld8bf(const __hip_bfloat16* p){ return *(const bf16x8*)p; }

__device__ __forceinline__ void cast8(const float* in, __hip_bfloat16* out) {
  const float4* p = (const float4*)in;
  float4 a = p[0], b = p[1];
  union { __hip_bfloat16 h[8]; int4 v; } o;
  o.h[0]=__float2bfloat16(a.x); o.h[1]=__float2bfloat16(a.y);
  o.h[2]=__float2bfloat16(a.z); o.h[3]=__float2bfloat16(a.w);
  o.h[4]=__float2bfloat16(b.x); o.h[5]=__float2bfloat16(b.y);
  o.h[6]=__float2bfloat16(b.z); o.h[7]=__float2bfloat16(b.w);
  *(int4*)out = o.v;
}

// ---------------- 256x256 bf16 MFMA GEMM, 2-phase interleave, counted vmcnt ----------------
// (round-8 schedule: best measured across 8 variants; 727us in_proj, MfmaUtil 37%, conflicts 0.
//  GEMM CLOSED.)
template<bool OUT_BF16>
__global__ __launch_bounds__(512)
void gemm_bf16_256(const __hip_bfloat16* __restrict__ A, const __hip_bfloat16* __restrict__ B,
                   void* __restrict__ Cout, int M, int N, int K) {
  const int nMt = M >> 8, nNt = N >> 8;
  const int nwg = nMt * nNt;
  const int cpx = nwg >> 3;
  const int lin = blockIdx.x;
  const int swz = (lin & 7) * cpx + (lin >> 3);   // XCD-chunked (nwg%8==0)
  const int mt = swz % nMt, ntile = swz / nMt;    // M fastest -> B panel L2-hot
  const int rowBase = mt << 8;
  const int colBase = ntile << 8;

  __shared__ short As[4][8192];   // 4 x 16KB
  __shared__ short Bs[4][8192];

  const int tid = threadIdx.x;
  const int lane = tid & 63, wid = tid >> 6;
  const int wr = wid >> 2, wc = wid & 3;          // 2M x 4N wave grid
  const int l15 = lane & 15, l4 = lane >> 4;

  const int r0 = tid >> 2,        c0 = (tid & 3) ^ ((r0 >> 1) & 3);
  const int r1 = (512+tid) >> 2,  c1 = ((512+tid) & 3) ^ ((r1 >> 1) & 3);
  const __hip_bfloat16* gA0 = A + (size_t)(rowBase + r0)*K + c0*8;
  const __hip_bfloat16* gA1 = A + (size_t)(rowBase + r1)*K + c1*8;
  const __hip_bfloat16* gB0 = B + (size_t)(colBase + r0)*K + c0*8;
  const __hip_bfloat16* gB1 = B + (size_t)(colBase + r1)*K + c1*8;
  const int ld0 = wid*512, ld1 = 4096 + wid*512;

#define STAGE_A(q, kt) do { \
    gload_lds16(gA0 + (size_t)(kt)*32, (void*)&As[q][ld0]); \
    gload_lds16(gA1 + (size_t)(kt)*32, (void*)&As[q][ld1]); \
  } while(0)
#define STAGE_B(q, kt) do { \
    gload_lds16(gB0 + (size_t)(kt)*32, (void*)&Bs[q][ld0]); \
    gload_lds16(gB1 + (size_t)(kt)*32, (void*)&Bs[q][ld1]); \
  } while(0)

  int aoff[8], boff[4];
  #pragma unroll
  for (int m=0;m<8;++m){ int r = wr*128 + m*16 + l15; aoff[m] = r*32 + ((l4 ^ ((r>>1)&3))*8); }
  #pragma unroll
  for (int n=0;n<4;++n){ int r = wc*64  + n*16 + l15; boff[n] = r*32 + ((l4 ^ ((r>>1)&3))*8); }

  f32x4 acc[8][4] = {};
  const int NKT = K >> 5;

  STAGE_A(0,0); STAGE_B(0,0);
  STAGE_A(1,1); STAGE_B(1,1);
  STAGE_A(2,2); STAGE_B(2,2);
  asm volatile("s_waitcnt vmcnt(8)" ::: "memory");
  __builtin_amdgcn_s_barrier();

  for (int t = 0; t < NKT; ++t) {
    const short* ab = &As[t&3][0];
    const short* bb = &Bs[t&3][0];
    const int q3 = (t+3)&3;
    bf16x8 a[4], b[4], a2[4];
    // phase A
    #pragma unroll
    for (int m=0;m<4;++m) a[m] = *(const bf16x8*)&ab[aoff[m]];
    #pragma unroll
    for (int n=0;n<4;++n) b[n] = *(const bf16x8*)&bb[boff[n]];
    if (t + 3 < NKT) STAGE_A(q3, t+3);
    __builtin_amdgcn_s_barrier();
    asm volatile("s_waitcnt lgkmcnt(0)" ::: "memory");
    __builtin_amdgcn_sched_barrier(0);
    __builtin_amdgcn_s_setprio(1);
    #pragma unroll
    for (int m=0;m<4;++m)
      #pragma unroll
      for (int n=0;n<4;++n)
        acc[m][n] = __builtin_amdgcn_mfma_f32_16x16x32_bf16(a[m], b[n], acc[m][n], 0, 0, 0);
    __builtin_amdgcn_s_setprio(0);
    __builtin_amdgcn_s_barrier();
    // phase B
    #pragma unroll
    for (int m=0;m<4;++m) a2[m] = *(const bf16x8*)&ab[aoff[m+4]];
    if (t + 3 < NKT) STAGE_B(q3, t+3);
    const int rem = NKT - 1 - t;
    if (rem >= 3)      asm volatile("s_waitcnt vmcnt(8)" ::: "memory");
    else if (rem == 2) asm volatile("s_waitcnt vmcnt(4)" ::: "memory");
    else if (rem == 1) asm volatile("s_waitcnt vmcnt(0)" ::: "memory");
    __builtin_amdgcn_s_barrier();
    asm volatile("s_waitcnt lgkmcnt(0)" ::: "memory");
    __builtin_amdgcn_sched_barrier(0);
    __builtin_amdgcn_s_setprio(1);
    #pragma unroll
    for (int m=0;m<4;++m)
      #pragma unroll
      for (int n=0;n<4;++n)
        acc[m+4][n] = __builtin_amdgcn_mfma_f32_16x16x32_bf16(a2[m], b[n], acc[m+4][n], 0, 0, 0);
    __builtin_amdgcn_s_setprio(0);
    __builtin_amdgcn_s_barrier();
  }
#undef STAGE_A
#undef STAGE_B

  #pragma unroll
  for (int m=0;m<8;++m) {
    int row0 = rowBase + wr*128 + m*16 + l4*4;
    #pragma unroll
    for (int n=0;n<4;++n) {
      int col = colBase + wc*64 + n*16 + l15;
      #pragma unroll
      for (int j=0;j<4;++j) {
        if (OUT_BF16)
          ((__hip_bfloat16*)Cout)[(size_t)(row0+j)*N + col] = __float2bfloat16(acc[m][n][j]);
        else
          ((float*)Cout)[(size_t)(row0+j)*N + col] = acc[m][n][j];
      }
    }
  }
}

// ---------------- fp32 dt GEMM, split-K; emits hs_bf AND both weight casts ----------------
__global__ __launch_bounds__(256)
void dt_gemm_splitk(const float* __restrict__ A, const float* __restrict__ B,
                    float* __restrict__ partial, __hip_bfloat16* __restrict__ hs_bf,
                    const float* __restrict__ w_in, __hip_bfloat16* __restrict__ w_in_bf,
                    const float* __restrict__ w_out, __hip_bfloat16* __restrict__ w_out_bf) {
  __shared__ float As[16][132];
  __shared__ float Bs[16][132];
  const int tid = threadIdx.x;
  const int tx = tid & 15, ty = tid >> 4;
  const int rowBase = blockIdx.y * 128;
  const int k0 = blockIdx.x * (HID/DTSK);
  float acc[8][8] = {};
  for (int kt = k0; kt < k0 + HID/DTSK; kt += 16) {
    for (int e = tid; e < 128*16; e += 256) {
      int r = e >> 4, c = e & 15;
      float av = A[(size_t)(rowBase + r) * HID + kt + c];
      As[c][r] = av;
      hs_bf[(size_t)(rowBase + r) * HID + kt + c] = __float2bfloat16(av);
      Bs[c][r] = B[(size_t)r * HID + kt + c];
    }
    __syncthreads();
    #pragma unroll
    for (int kk = 0; kk < 16; ++kk) {
      float a[8], bv[8];
      #pragma unroll
      for (int i = 0; i < 8; ++i) a[i] = As[kk][ty*8+i];
      #pragma unroll
      for (int j = 0; j < 8; ++j) bv[j] = Bs[kk][tx*8+j];
      #pragma unroll
      for (int i = 0; i < 8; ++i)
        #pragma unroll
        for (int j = 0; j < 8; ++j)
          acc[i][j] += a[i]*bv[j];
    }
    __syncthreads();
  }
  float* outp = partial + (size_t)blockIdx.x * NT * NH;
  for (int i = 0; i < 8; ++i) {
    size_t ro = (size_t)(rowBase + ty*8 + i) * NH + tx*8;
    #pragma unroll
    for (int j = 0; j < 8; ++j) outp[ro + j] = acc[i][j];
  }
  // ---- fused weight casts (grid-stride over both weight matrices) ----
  {
    const size_t n1 = (size_t)ZXW*HID/8;
    const size_t n2 = (size_t)HID*DIN/8;
    const size_t ntot = n1 + n2;
    size_t gid = ((size_t)blockIdx.y * gridDim.x + blockIdx.x) * 256 + tid;
    size_t gsz = (size_t)gridDim.x * gridDim.y * 256;
    for (size_t i = gid; i < ntot; i += gsz) {
      if (i < n1)  cast8(w_in + i*8,      w_in_bf + i*8);
      else         cast8(w_out+ (i-n1)*8, w_out_bf+ (i-n1)*8);
    }
  }
}

// ---------------- dt: split-K reduce + softplus + per-chunk cumsum ----------------
__global__ __launch_bounds__(256)
void dt_scan_kernel(const float* __restrict__ partial, const float* __restrict__ dt_bias,
                    const float* __restrict__ A_log, float* __restrict__ dt_sp,
                    float* __restrict__ Acs) {
  int bid = blockIdx.x;       // (b*NH + h)*NC + c
  int c = bid % NC;
  int h = (bid / NC) % NH;
  int b = bid / (NC*NH);
  int k = threadIdx.x;
  int t = b*SEQ + c*CS + k;
  float raw = dt_bias[h];
  #pragma unroll
  for (int sk = 0; sk < DTSK; ++sk) raw += partial[(size_t)sk*NT*NH + (size_t)t*NH + h];
  float dtv = softplusf_(raw);
  dt_sp[(size_t)t*NH + h] = dtv;
  float adt = -expf(A_log[h]) * dtv;
  __shared__ float s[CS];
  s[k] = adt;
  __syncthreads();
  for (int off = 1; off < CS; off <<= 1) {
    float v = (k >= off) ? s[k-off] : 0.f;
    __syncthreads();
    s[k] += v;
    __syncthreads();
  }
  Acs[((size_t)(b*NH + h)*NC + c)*CS + k] = s[k];
}

// ---------------- fused conv+SiLU + transpose + dt scaling ----------------
__global__ __launch_bounds__(256)
void conv_fused_kernel(const __hip_bfloat16* __restrict__ zx, const float* __restrict__ w,
                       const float* __restrict__ bias,
                       const float* __restrict__ dt_sp, const float* __restrict__ Acs,
                       __hip_bfloat16* __restrict__ xsT, __hip_bfloat16* __restrict__ xwT,
                       __hip_bfloat16* __restrict__ Bbf, __hip_bfloat16* __restrict__ Cbf,
                       __hip_bfloat16* __restrict__ BT) {
  const int tt = blockIdx.x;
  const int ct = blockIdx.y;
  const int t0 = tt*64;
  const int ch0 = ct*64;
  const int tid = threadIdx.x;
  __shared__ unsigned short T[64][72];
  __shared__ float dts[64], ews[64];

  const bool isX = (ch0 < DIN);
  const bool isB = (ch0 >= DIN) && (ch0 < DIN + G*NSTATE);

  if (isX && tid < 64) {
    int h = ch0 >> 6;
    int t = t0 + tid;
    dts[tid] = dt_sp[(size_t)t*NH + h];
    int b = t0 >> 11, cc = (t0 >> 8) & 7, k0 = t0 & 255;
    const float* acs = Acs + ((size_t)(b*NH+h)*NC + cc)*CS;
    ews[tid] = __expf(acs[CS-1] - acs[k0 + tid]);
  }

  const int l0 = t0 & (SEQ-1);
  #pragma unroll
  for (int it = 0; it < 2; ++it) {
    int r = tid >> 2;
    int c8 = (tid & 3) + it*4;
    int cb = ch0 + c8*8;
    float acc[8];
    *(float4*)&acc[0] = *(const float4*)&bias[cb];
    *(float4*)&acc[4] = *(const float4*)&bias[cb+4];
    float4 wv[8];
    #pragma unroll
    for (int q=0;q<8;++q) wv[q] = *(const float4*)&w[(cb+q)*4];
    #pragma unroll
    for (int k=0;k<4;++k) {
      if (l0 + r - 3 + k >= 0) {
        u16x8 v = *(const u16x8*)&zx[(size_t)(t0+r-3+k)*ZXW + DIN + cb];
        #pragma unroll
        for (int q=0;q<8;++q) acc[q] += b2f(v[q]) * ((const float*)&wv[q])[k];
      }
    }
    u16x8 o;
    #pragma unroll
    for (int q=0;q<8;++q) o[q] = f2b(siluf_(acc[q]));
    if (isX || isB) {
      #pragma unroll
      for (int q=0;q<8;++q) T[c8*8+q][r] = o[q];
    }
    if (!isX) {
      if (isB) *(u16x8*)&Bbf[(size_t)(t0+r)*(G*NSTATE) + (cb - DIN)] = o;
      else     *(u16x8*)&Cbf[(size_t)(t0+r)*(G*NSTATE) + (cb - DIN - G*NSTATE)] = o;
    }
  }
  if (!isX && !isB) return;
  __syncthreads();
  #pragma unroll
  for (int it = 0; it < 2; ++it) {
    int ch = tid >> 2;
    int tc = (tid & 3) + it*4;
    u16x8 v = *(const u16x8*)&T[ch][tc*8];
    if (isX) {
      u16x8 a, wv2;
      #pragma unroll
      for (int q=0;q<8;++q) {
        float f = b2f(v[q]);
        float fs = f * dts[tc*8+q];
        a[q]   = f2b(fs);
        wv2[q] = f2b(fs * ews[tc*8+q]);
      }
      *(u16x8*)&xsT[(size_t)(ch0+ch)*NT + t0 + tc*8] = a;
      *(u16x8*)&xwT[(size_t)(ch0+ch)*NT + t0 + tc*8] = wv2;
    } else {
      *(u16x8*)&BT[(size_t)(ch0 - DIN + ch)*NT + t0 + tc*8] = v;
    }
  }
}

// ---------------- chunk states + recurrence, fused (round-19 version: best measured) ----------------
__global__ __launch_bounds__(256)
void chunk_states_fused(const __hip_bfloat16* __restrict__ xwT, const __hip_bfloat16* __restrict__ BT,
                        const float* __restrict__ Acs, __hip_bfloat16* __restrict__ states_bf) {
  int h = blockIdx.x, b = blockIdx.y;
  int g = h >> 4;
  int tid = threadIdx.x, lane = tid & 63, w = tid >> 6;
  int l15 = lane & 15, l4 = lane >> 4;
  int n0 = w*32;
  f32x4 S[4][2] = {};
  for (int c = 0; c < NC; ++c) {
    int tbase = b*SEQ + c*CS;
    const __hip_bfloat16* xp = xwT + (size_t)(h*64 + l15)*NT + tbase + l4*8;
    const __hip_bfloat16* bp = BT + (size_t)(g*128 + n0 + l15)*NT + tbase + l4*8;
    f32x4 acc[4][2] = {};
    for (int kc = 0; kc < 8; ++kc) {
      bf16x8 xf[4], bf2[2];
      #pragma unroll
      for (int tm=0;tm<4;++tm) xf[tm] = ld8bf(xp + (size_t)(tm*16)*NT + kc*32);
      #pragma unroll
      for (int tn=0;tn<2;++tn) bf2[tn] = ld8bf(bp + (size_t)(tn*16)*NT + kc*32);
      #pragma unroll
      for (int tm=0;tm<4;++tm)
        #pragma unroll
        for (int tn=0;tn<2;++tn)
          acc[tm][tn] = __builtin_amdgcn_mfma_f32_16x16x32_bf16(xf[tm], bf2[tn], acc[tm][tn], 0, 0, 0);
    }
    __hip_bfloat16* out = states_bf + ((size_t)(b*NC + c)*NH + h)*(HD*NSTATE);
    float decay = expf(Acs[((size_t)(b*NH+h)*NC + c)*CS + CS-1]);
    #pragma unroll
    for (int tm=0;tm<4;++tm)
      #pragma unroll
      for (int tn=0;tn<2;++tn)
        #pragma unroll
        for (int q=0;q<4;++q) {
          out[(size_t)(tm*16 + l4*4 + q)*NSTATE + n0 + tn*16 + l15] = __float2bfloat16(S[tm][tn][q]);
          S[tm][tn][q] = S[tm][tn][q]*decay + acc[tm][tn][q];
        }
  }
}

// ---------------- Y via MFMA — load-balanced 32-row i-tiles ----------------
__global__ __launch_bounds__(256)
void y_mfma_kernel(const __hip_bfloat16* __restrict__ zx,
                   const __hip_bfloat16* __restrict__ Cn,
                   const __hip_bfloat16* __restrict__ Bn,
                   const __hip_bfloat16* __restrict__ xsT,
                   const __hip_bfloat16* __restrict__ Sbf,
                   const float* __restrict__ dt_sp,
                   const float* __restrict__ Acs,
                   const float* __restrict__ Dp,
                   __hip_bfloat16* __restrict__ ybf) {
  int h = blockIdx.x;
  int bc = blockIdx.y;
  int c = bc & 7, b = bc >> 3;
  int g = h >> 4;
  int tbase = b*SEQ + c*CS;
  int tid = threadIdx.x, lane = tid & 63, w = tid >> 6;
  int l15 = lane & 15, l4 = lane >> 4;
  __shared__ float acs_s[CS];
  __shared__ unsigned short P[4][32][40];   // per-wave 32x32 P tile
  acs_s[tid] = Acs[((size_t)(b*NH+h)*NC + c)*CS + tid];
  __syncthreads();

  float Dh = Dp[h];
  const __hip_bfloat16* Cbase = Cn + (size_t)tbase*1024 + g*128;
  const __hip_bfloat16* Bbase = Bn + (size_t)tbase*1024 + g*128;
  const __hip_bfloat16* xbase = xsT + (size_t)(h*64 + l15)*NT + tbase;
  const __hip_bfloat16* Sb = Sbf + ((size_t)bc*NH + h)*(HD*NSTATE);

  for (int tix = 0; tix < 2; ++tix) {
    const int kt = tix ? (7 - w) : w;        // owned 32-row i-tile index
    const int i0 = kt * 32;
    float acs_i[2], rd2[2];
    #pragma unroll
    for (int ti=0;ti<2;++ti) {
      int ig = i0 + ti*16 + l15;
      acs_i[ti] = acs_s[ig];
      rd2[ti] = Dh / dt_sp[(size_t)(tbase+ig)*NH + h];
    }
    bf16x8 cfr[4][2];   // [kc][ti], reused for scores and Y_off
    #pragma unroll
    for (int kc = 0; kc < 4; ++kc)
      #pragma unroll
      for (int ti=0;ti<2;++ti)
        cfr[kc][ti] = ld8bf(Cbase + (size_t)(i0 + ti*16 + l15)*1024 + kc*32 + l4*8);

    f32x4 accY[4][2] = {};
    for (int jb = 0; jb <= kt; ++jb) {
      int j0 = jb*32;
      f32x4 sacc[2][2] = {};
      for (int kc = 0; kc < 4; ++kc) {
        bf16x8 bfr[2];
        #pragma unroll
        for (int tj=0;tj<2;++tj) bfr[tj] = ld8bf(Bbase + (size_t)(j0 + tj*16 + l15)*1024 + kc*32 + l4*8);
        #pragma unroll
        for (int tj=0;tj<2;++tj)
          #pragma unroll
          for (int ti=0;ti<2;++ti)
            sacc[tj][ti] = __builtin_amdgcn_mfma_f32_16x16x32_bf16(bfr[tj], cfr[kc][ti], sacc[tj][ti], 0, 0, 0);
      }
      if (jb < kt) {
        #pragma unroll
        for (int tj=0;tj<2;++tj)
          #pragma unroll
          for (int ti=0;ti<2;++ti) {
            float ai = acs_i[ti];
            u16x4 pk;
            #pragma unroll
            for (int q=0;q<4;++q) {
              int jg = j0 + tj*16 + l4*4 + q;
              pk[q] = f2b(sacc[tj][ti][q] * __expf(ai - acs_s[jg]));
            }
            *(u16x4*)&P[w][ti*16 + l15][tj*16 + l4*4] = pk;
          }
      } else {
        #pragma unroll
        for (int tj=0;tj<2;++tj)
          #pragma unroll
          for (int ti=0;ti<2;++ti) {
            int ig = i0 + ti*16 + l15;
            float ai = acs_i[ti];
            u16x4 pk;
            #pragma unroll
            for (int q=0;q<4;++q) {
              int jg = j0 + tj*16 + l4*4 + q;
              float v = (jg <= ig) ? sacc[tj][ti][q] * __expf(ai - acs_s[jg]) : 0.f;
              if (jg == ig) v += rd2[ti];
              pk[q] = f2b(v);
            }
            *(u16x4*)&P[w][ti*16 + l15][tj*16 + l4*4] = pk;
          }
      }
      // PV: one K=32 step over this 32-j block
      bf16x8 xf[4], pf[2];
      #pragma unroll
      for (int tm=0;tm<4;++tm) xf[tm] = ld8bf(xbase + (size_t)(tm*16)*NT + j0 + l4*8);
      #pragma unroll
      for (int ti=0;ti<2;++ti) pf[ti] = *(const bf16x8*)&P[w][ti*16 + l15][l4*8];
      #pragma unroll
      for (int tm=0;tm<4;++tm)
        #pragma unroll
        for (int ti=0;ti<2;++ti)
          accY[tm][ti] = __builtin_amdgcn_mfma_f32_16x16x32_bf16(xf[tm], pf[ti], accY[tm][ti], 0, 0, 0);
    }
    // Y_off: reuse cfr
    f32x4 oacc[4][2] = {};
    #pragma unroll
    for (int kc = 0; kc < 4; ++kc) {
      bf16x8 sf[4];
      #pragma unroll
      for (int tm=0;tm<4;++tm) sf[tm] = ld8bf(Sb + (size_t)(tm*16 + l15)*NSTATE + kc*32 + l4*8);
      #pragma unroll
      for (int tm=0;tm<4;++tm)
        #pragma unroll
        for (int ti=0;ti<2;++ti)
          oacc[tm][ti] = __builtin_amdgcn_mfma_f32_16x16x32_bf16(sf[tm], cfr[kc][ti], oacc[tm][ti], 0, 0, 0);
    }
    // epilogue for this tile
    #pragma unroll
    for (int ti=0;ti<2;++ti) {
      int ig = i0 + ti*16 + l15;
      int t = tbase + ig;
      float sd = __expf(acs_i[ti]);
      #pragma unroll
      for (int tm=0;tm<4;++tm) {
        int ch0 = h*64 + tm*16 + l4*4;
        u16x4 gv = *(const u16x4*)&zx[(size_t)t*ZXW + ch0];
        u16x4 out;
        #pragma unroll
        for (int q=0;q<4;++q) {
          float yv = accY[tm][ti][q] + sd * oacc[tm][ti][q];
          yv *= siluf_(b2f(gv[q]));
          out[q] = f2b(yv);
        }
        *(u16x4*)&ybf[(size_t)t*DIN + ch0] = out;
      }
    }
  }
}

// ---------------- RMS groupnorm, bf16 in-place ----------------
__global__ __launch_bounds__(256)
void groupnorm_bf16_kernel(unsigned short* __restrict__ y, const float* __restrict__ norm_w) {
  int bid = blockIdx.x;
  int g = bid % G;
  int t = bid / G;
  unsigned short* yp = y + (size_t)t*DIN + g*GROUP_SIZE;
  int tid = threadIdx.x;
  u16x4 v = *(const u16x4*)&yp[tid*4];
  float f[4]; float ss = 0.f;
  #pragma unroll
  for (int j=0;j<4;++j) { f[j] = b2f(v[j]); ss += f[j]*f[j]; }
  #pragma unroll
  for (int off = 32; off > 0; off >>= 1) ss += __shfl_xor(ss, off);
  __shared__ float wsum[4];
  int wave = tid >> 6;
  if ((tid & 63) == 0) wsum[wave] = ss;
  __syncthreads();
  float tot = wsum[0]+wsum[1]+wsum[2]+wsum[3];
  float rs = rsqrtf(tot/(float)GROUP_SIZE + 1e-5f);
  const float* nw = norm_w + g*GROUP_SIZE + tid*4;
  u16x4 o;
  #pragma unroll
  for (int j=0;j<4;++j) o[j] = f2b(f[j] * rs * nw[j]);
  *(u16x4*)&yp[tid*4] = o;
}

extern "C" void kernel_launch(void* const* d_in, const int* in_sizes, int n_in,
                              void* d_out, int out_size, void* d_ws, size_t ws_size,
                              hipStream_t stream) {
  const float* hs        = (const float*)d_in[0];
  const float* in_proj_w = (const float*)d_in[1];
  const float* conv_w    = (const float*)d_in[2];
  const float* conv_b    = (const float*)d_in[3];
  const float* dt_bias   = (const float*)d_in[4];
  const float* A_log     = (const float*)d_in[5];
  const float* Dp        = (const float*)d_in[6];
  const float* norm_w    = (const float*)d_in[7];
  const float* out_proj_w= (const float*)d_in[8];
  float* outp = (float*)d_out;

  char* ws = (char*)d_ws;
  __hip_bfloat16* zx_bf = (__hip_bfloat16*)ws;                      // NT*ZXW*2 = 150,994,944
  char* p = ws + (size_t)NT*ZXW*2;
  __hip_bfloat16* B_bf  = (__hip_bfloat16*)p; p += (size_t)NT*G*NSTATE*2;
  __hip_bfloat16* C_bf  = (__hip_bfloat16*)p; p += (size_t)NT*G*NSTATE*2;
  __hip_bfloat16* BT    = (__hip_bfloat16*)p; p += (size_t)NT*G*NSTATE*2;
  __hip_bfloat16* y_bf  = (__hip_bfloat16*)p; p += (size_t)NT*DIN*2;
  float* dtb    = (float*)p;  p += (size_t)NT*NH*4;
  float* Acs    = (float*)p;  p += (size_t)BATCH*NH*NC*CS*4;
  float* dt_part = (float*)y_bf;     // aliases y_bf (dead until y_mfma)
  char* F = p;
  __hip_bfloat16* w_in_bf   = (__hip_bfloat16*)F;
  __hip_bfloat16* xsT       = (__hip_bfloat16*)F;
  __hip_bfloat16* xwT       = (__hip_bfloat16*)(F + 67108864);
  __hip_bfloat16* hs_bf     = (__hip_bfloat16*)(F + 150994944);
  __hip_bfloat16* states_bf = (__hip_bfloat16*)(F + 150994944);
  char* F2 = F + 150994944 + 33554432;
  __hip_bfloat16* w_out_bf  = (__hip_bfloat16*)F2;

  // dt GEMM (fp32) + hs cast + both weight casts, all in one launch
  dt_gemm_splitk<<<dim3(DTSK, NT/128), 256, 0, stream>>>(
      hs, in_proj_w + (size_t)ZXW*HID, dt_part, hs_bf,
      in_proj_w, w_in_bf, out_proj_w, w_out_bf);
  dt_scan_kernel<<<BATCH*NH*NC, CS, 0, stream>>>(dt_part, dt_bias, A_log, dtb, Acs);

  gemm_bf16_256<true><<<dim3((NT/256)*(ZXW/256)), 512, 0, stream>>>(
      hs_bf, w_in_bf, zx_bf, NT, ZXW, HID);

  conv_fused_kernel<<<dim3(NT/64, CONV_DIM/64), 256, 0, stream>>>(
      zx_bf, conv_w, conv_b, dtb, Acs, xsT, xwT, B_bf, C_bf, BT);

  chunk_states_fused<<<dim3(NH, BATCH), 256, 0, stream>>>(xwT, BT, Acs, states_bf);

  y_mfma_kernel<<<dim3(NH, BATCH*NC), 256, 0, stream>>>(zx_bf, C_bf, B_bf, xsT, states_bf, dtb, Acs, Dp, y_bf);
  groupnorm_bf16_kernel<<<NT*G, 256, 0, stream>>>((unsigned short*)y_bf, norm_w);

  gemm_bf16_256<false><<<dim3((NT/256)*(HID/256)), 512, 0, stream>>>(
      y_bf, w_out_bf, outp, NT, HID, DIN);
}